// Round 3
// baseline (776.895 us; speedup 1.0000x reference)
//
#include <hip/hip_runtime.h>

typedef unsigned short u16;
typedef unsigned int u32;
typedef __attribute__((ext_vector_type(8))) short short8;   // 8 bf16 MFMA frag
typedef __attribute__((ext_vector_type(4))) float f32x4;
typedef __attribute__((ext_vector_type(2))) unsigned int u32x2;

#define BB 4
#define CC 256
#define NT 4096
#define L2E 1.4426950408889634f

__device__ __forceinline__ float b2f(u16 v) {
    union { u32 u; float f; } c; c.u = ((u32)v) << 16; return c.f;
}
__device__ __forceinline__ u16 f2b(float f) {
    union { float f; u32 u; } c; c.f = f;
    u32 u = c.u;
    return (u16)((u + 0x7fffu + ((u >> 16) & 1u)) >> 16);   // RNE
}
#define MFMA16(A, B, C) __builtin_amdgcn_mfma_f32_16x16x32_bf16(A, B, C, 0, 0, 0)

// pack 8 consecutive fp32 (two f32x4) into a bf16 short8 frag, round-to-nearest
__device__ __forceinline__ short8 pack8(f32x4 a, f32x4 b) {
    union { f32x4 f; u32 u[4]; } A, Bu; A.f = a; Bu.f = b;
    union { u32 u[4]; short8 s; } R;
    R.u[0] = __builtin_amdgcn_perm(A.u[1]  + 0x8000u, A.u[0]  + 0x8000u, 0x07060302u);
    R.u[1] = __builtin_amdgcn_perm(A.u[3]  + 0x8000u, A.u[2]  + 0x8000u, 0x07060302u);
    R.u[2] = __builtin_amdgcn_perm(Bu.u[1] + 0x8000u, Bu.u[0] + 0x8000u, 0x07060302u);
    R.u[3] = __builtin_amdgcn_perm(Bu.u[3] + 0x8000u, Bu.u[2] + 0x8000u, 0x07060302u);
    return R.s;
}

// ---------------------------------------------------------------------------
// kwsplit: W=[Wq;Wk;Wv] (320x256 fp32) -> wh/wl bf16 Dekker split, row-major.
// ---------------------------------------------------------------------------
__global__ __launch_bounds__(256) void kwsplit(
    const float* __restrict__ Wq, const float* __restrict__ Wk,
    const float* __restrict__ Wv, u16* __restrict__ wh, u16* __restrict__ wl)
{
    const int e = blockIdx.x * 256 + threadIdx.x;          // 0..81919
    const int m = e >> 8, k = e & 255;
    float v;
    if (m < 32)      v = Wq[m * 256 + k];
    else if (m < 64) v = Wk[(m - 32) * 256 + k];
    else             v = Wv[(m - 64) * 256 + k];
    const u16 h = f2b(v);
    wh[e] = h; wl[e] = f2b(v - b2f(h));
}

// ---------------------------------------------------------------------------
// kcast: x fp32 [b][c][n] -> xth/xtl bf16 [b][n][c] (transposed, c contig).
// 32x32 LDS tile transpose, coalesced both sides.
// ---------------------------------------------------------------------------
__global__ __launch_bounds__(256) void kcast(
    const float* __restrict__ x, u16* __restrict__ xth, u16* __restrict__ xtl)
{
    __shared__ float lT[32][33];
    const int b = blockIdx.z, c0 = blockIdx.y * 32, n0 = blockIdx.x * 32;
    const int t = threadIdx.x;
    const int lr = t >> 3, lc4 = (t & 7) * 4;
    f32x4 v = *(const f32x4*)(x + ((size_t)(b * CC + c0 + lr)) * NT + n0 + lc4);
    #pragma unroll
    for (int j = 0; j < 4; ++j) lT[lr][lc4 + j] = v[j];
    __syncthreads();
    // write: n-row = lr, c chunk = lc4
    u16 h[4], l[4];
    #pragma unroll
    for (int j = 0; j < 4; ++j) {
        float f = lT[lc4 + j][lr];
        h[j] = f2b(f); l[j] = f2b(f - b2f(h[j]));
    }
    const size_t o = ((size_t)(b * NT + n0 + lr)) * CC + c0 + lc4;
    u32x2 ph, pl;
    ph[0] = (u32)h[0] | ((u32)h[1] << 16); ph[1] = (u32)h[2] | ((u32)h[3] << 16);
    pl[0] = (u32)l[0] | ((u32)l[1] << 16); pl[1] = (u32)l[2] | ((u32)l[3] << 16);
    *(u32x2*)(xth + o) = ph;
    *(u32x2*)(xtl + o) = pl;
}

// ---------------------------------------------------------------------------
// kproj (MFMA): Y = Wsplit @ xsplit, 3 MFMAs per tile (wh*xh + wl*xh + wh*xl).
// 1-wave blocks, wave = 32m x 32n, direct global frag loads (L2-resident).
// Outputs: qh/ql, kh/kl [b][n][32] (o contig); pvw [b][c][n] bf16.
// ---------------------------------------------------------------------------
__global__ __launch_bounds__(64) void kproj(
    const u16* __restrict__ wh, const u16* __restrict__ wl,
    const u16* __restrict__ xth, const u16* __restrict__ xtl,
    const float* __restrict__ bq, const float* __restrict__ bk,
    const float* __restrict__ bv,
    u16* __restrict__ qh, u16* __restrict__ ql,
    u16* __restrict__ kh, u16* __restrict__ kl, u16* __restrict__ pvw)
{
    const int b = blockIdx.z, m0 = blockIdx.y * 32, n0 = blockIdx.x * 32;
    const int lane = threadIdx.x, quad = lane >> 4, l16 = lane & 15;

    const u16* awh0 = wh + (m0 + l16) * 256 + quad * 8;
    const u16* awl0 = wl + (m0 + l16) * 256 + quad * 8;
    const size_t xoff = ((size_t)(b * NT + n0 + l16)) * CC + quad * 8;
    const u16* bxh0 = xth + xoff;
    const u16* bxl0 = xtl + xoff;

    f32x4 a00 = {0,0,0,0}, a01 = {0,0,0,0}, a10 = {0,0,0,0}, a11 = {0,0,0,0};
    #pragma unroll 2
    for (int k0 = 0; k0 < 256; k0 += 32) {
        short8 Ah0 = *(const short8*)(awh0 + k0);
        short8 Ah1 = *(const short8*)(awh0 + 16 * 256 + k0);
        short8 Al0 = *(const short8*)(awl0 + k0);
        short8 Al1 = *(const short8*)(awl0 + 16 * 256 + k0);
        short8 Bh0 = *(const short8*)(bxh0 + k0);
        short8 Bh1 = *(const short8*)(bxh0 + 16 * CC + k0);
        short8 Bl0 = *(const short8*)(bxl0 + k0);
        short8 Bl1 = *(const short8*)(bxl0 + 16 * CC + k0);
        a00 = MFMA16(Ah0, Bh0, a00); a00 = MFMA16(Al0, Bh0, a00); a00 = MFMA16(Ah0, Bl0, a00);
        a01 = MFMA16(Ah0, Bh1, a01); a01 = MFMA16(Al0, Bh1, a01); a01 = MFMA16(Ah0, Bl1, a01);
        a10 = MFMA16(Ah1, Bh0, a10); a10 = MFMA16(Al1, Bh0, a10); a10 = MFMA16(Ah1, Bl0, a10);
        a11 = MFMA16(Ah1, Bh1, a11); a11 = MFMA16(Al1, Bh1, a11); a11 = MFMA16(Ah1, Bl1, a11);
    }

    #pragma unroll
    for (int i = 0; i < 2; ++i) {
        #pragma unroll
        for (int j = 0; j < 2; ++j) {
            f32x4 acc = (i == 0) ? ((j == 0) ? a00 : a01) : ((j == 0) ? a10 : a11);
            #pragma unroll
            for (int r = 0; r < 4; ++r) {
                const int m = m0 + i * 16 + quad * 4 + r;
                const int n = n0 + j * 16 + l16;
                const float bias = (m < 32) ? bq[m] : (m < 64) ? bk[m - 32] : bv[m - 64];
                const float val = acc[r] + bias;
                if (m < 32) {
                    const size_t idx = ((size_t)(b * NT + n)) * 32 + m;
                    const u16 h = f2b(val);
                    qh[idx] = h; ql[idx] = f2b(val - b2f(h));
                } else if (m < 64) {
                    const size_t idx = ((size_t)(b * NT + n)) * 32 + (m - 32);
                    const u16 h = f2b(val);
                    kh[idx] = h; kl[idx] = f2b(val - b2f(h));
                } else {
                    pvw[((size_t)(b * CC + m - 64)) * NT + n] = f2b(val);
                }
            }
        }
    }
}

// ---------------------------------------------------------------------------
// kattn: energy + masked renormalized softmax -> sa fp32 (d_out chunk 1).
// Block = 4 waves x 16 rows = 64 rows. kh/kl staged per 128-col tile in LDS
// (shared by all 4 waves, 16x traffic cut), register-prefetched 1 tile ahead.
// ---------------------------------------------------------------------------
__global__ __launch_bounds__(256) void kattn(
    const u16* __restrict__ qh, const u16* __restrict__ ql,
    const u16* __restrict__ kh, const u16* __restrict__ kl,
    const float* __restrict__ valid, float* __restrict__ sa)
{
    __shared__ __align__(16) u16 lKh[128][40];   // pad 40: 80B stride, 16B-aligned frags
    __shared__ __align__(16) u16 lKl[128][40];
    __shared__ float lV[128];
    const int b = blockIdx.y;
    const int t = threadIdx.x;
    const int lane = t & 63, wv = t >> 6;
    const int quad = lane >> 4, l16 = lane & 15;
    const int r0 = blockIdx.x * 64 + wv * 16;

    const size_t abase = ((size_t)(b * NT + r0 + l16)) * 32 + quad * 8;
    const short8 aqh = *(const short8*)(qh + abase);
    const short8 aql = *(const short8*)(ql + abase);

    const int scol = t >> 1, skb = (t & 1) * 16;     // staging: col, k-chunk
    const u16* khp = kh + ((size_t)(b * NT + scol)) * 32 + skb;
    const u16* klp = kl + ((size_t)(b * NT + scol)) * 32 + skb;
    const float* vp = valid + b * NT;
    const f32x4 zero = {0.f, 0.f, 0.f, 0.f};

    short8 h0, h1, g0, g1; float vv;
    // prefetch tile 0
    h0 = *(const short8*)(khp); h1 = *(const short8*)(khp + 8);
    g0 = *(const short8*)(klp); g1 = *(const short8*)(klp + 8);
    vv = (t < 128) ? vp[t] : 0.f;

    float sacc[4] = {0.f, 0.f, 0.f, 0.f};
    for (int ct = 0; ct < 32; ++ct) {
        __syncthreads();
        *(short8*)&lKh[scol][skb] = h0; *(short8*)&lKh[scol][skb + 8] = h1;
        *(short8*)&lKl[scol][skb] = g0; *(short8*)&lKl[scol][skb + 8] = g1;
        if (t < 128) lV[t] = vv;
        __syncthreads();
        if (ct < 31) {
            const u16* p1 = khp + (size_t)(ct + 1) * 128 * 32;
            const u16* p2 = klp + (size_t)(ct + 1) * 128 * 32;
            h0 = *(const short8*)(p1); h1 = *(const short8*)(p1 + 8);
            g0 = *(const short8*)(p2); g1 = *(const short8*)(p2 + 8);
            if (t < 128) vv = vp[(ct + 1) * 128 + t];
        }
        #pragma unroll
        for (int s = 0; s < 8; ++s) {
            short8 bh = *(const short8*)&lKh[s * 16 + l16][quad * 8];
            short8 bl = *(const short8*)&lKl[s * 16 + l16][quad * 8];
            f32x4 d = MFMA16(aqh, bh, zero);
            d = MFMA16(aql, bh, d);
            d = MFMA16(aqh, bl, d);
            const float vc = lV[s * 16 + l16];
            #pragma unroll
            for (int i = 0; i < 4; ++i)
                sacc[i] += vc * exp2f(fminf(d[i], 60.f) * L2E);
        }
    }
    #pragma unroll
    for (int i = 0; i < 4; ++i) {
        #pragma unroll
        for (int off = 1; off < 16; off <<= 1)
            sacc[i] += __shfl_xor(sacc[i], off, 64);
        sacc[i] = 1.0f / sacc[i];
    }
    // pass 2: recompute + emit
    h0 = *(const short8*)(khp); h1 = *(const short8*)(khp + 8);
    g0 = *(const short8*)(klp); g1 = *(const short8*)(klp + 8);
    vv = (t < 128) ? vp[t] : 0.f;
    for (int ct = 0; ct < 32; ++ct) {
        __syncthreads();
        *(short8*)&lKh[scol][skb] = h0; *(short8*)&lKh[scol][skb + 8] = h1;
        *(short8*)&lKl[scol][skb] = g0; *(short8*)&lKl[scol][skb + 8] = g1;
        if (t < 128) lV[t] = vv;
        __syncthreads();
        if (ct < 31) {
            const u16* p1 = khp + (size_t)(ct + 1) * 128 * 32;
            const u16* p2 = klp + (size_t)(ct + 1) * 128 * 32;
            h0 = *(const short8*)(p1); h1 = *(const short8*)(p1 + 8);
            g0 = *(const short8*)(p2); g1 = *(const short8*)(p2 + 8);
            if (t < 128) vv = vp[(ct + 1) * 128 + t];
        }
        #pragma unroll
        for (int s = 0; s < 8; ++s) {
            short8 bh = *(const short8*)&lKh[s * 16 + l16][quad * 8];
            short8 bl = *(const short8*)&lKl[s * 16 + l16][quad * 8];
            f32x4 d = MFMA16(aqh, bh, zero);
            d = MFMA16(aql, bh, d);
            d = MFMA16(aqh, bl, d);
            const float vc = lV[s * 16 + l16];
            const int col = ct * 128 + s * 16 + l16;
            #pragma unroll
            for (int i = 0; i < 4; ++i) {
                const float val = vc * exp2f(fminf(d[i], 60.f) * L2E) * sacc[i];
                sa[((size_t)(b * NT + r0 + quad * 4 + i)) * NT + col] = val;
            }
        }
    }
}

// ---------------------------------------------------------------------------
// kout: out[b,c,m] = gamma * sum_n pv[c,n]*sa[m,n] + x[c,m].  BARRIER-FREE.
// B-frags built in-register from fp32 sa (dwordx4 x2 + v_perm RNE pack);
// A-frags direct bf16. 6 independent load streams -> compiler pipelines.
// ---------------------------------------------------------------------------
__global__ __launch_bounds__(512) void kout(
    const u16* __restrict__ pvw, const float* __restrict__ sa,
    const float* __restrict__ x, const float* __restrict__ gamma,
    float* __restrict__ outp)
{
    const int b = blockIdx.y, m0 = blockIdx.x * 32;
    const int t = threadIdx.x, lane = t & 63, wv = t >> 6;
    const int c0 = wv * 32, quad = lane >> 4, l16 = lane & 15;

    const u16* a0p = pvw + ((size_t)(b * CC + c0 + l16)) * NT + quad * 8;
    const u16* a1p = a0p + (size_t)16 * NT;
    const float* b0p = sa + ((size_t)(b * NT + m0 + l16)) * NT + quad * 8;
    const float* b1p = b0p + (size_t)16 * NT;

    f32x4 acc00 = {0,0,0,0}, acc01 = {0,0,0,0}, acc10 = {0,0,0,0}, acc11 = {0,0,0,0};
    #pragma unroll 2
    for (int k0 = 0; k0 < NT; k0 += 32) {
        short8 a0 = *(const short8*)(a0p + k0);
        short8 a1 = *(const short8*)(a1p + k0);
        f32x4 s00 = *(const f32x4*)(b0p + k0), s01 = *(const f32x4*)(b0p + k0 + 4);
        f32x4 s10 = *(const f32x4*)(b1p + k0), s11 = *(const f32x4*)(b1p + k0 + 4);
        short8 bf0 = pack8(s00, s01);
        short8 bf1 = pack8(s10, s11);
        acc00 = MFMA16(a0, bf0, acc00);
        acc01 = MFMA16(a0, bf1, acc01);
        acc10 = MFMA16(a1, bf0, acc10);
        acc11 = MFMA16(a1, bf1, acc11);
    }

    const float g = gamma[0];
    #pragma unroll
    for (int ai = 0; ai < 2; ++ai) {
        #pragma unroll
        for (int bi = 0; bi < 2; ++bi) {
            f32x4 acc = (ai == 0) ? ((bi == 0) ? acc00 : acc01)
                                  : ((bi == 0) ? acc10 : acc11);
            #pragma unroll
            for (int i = 0; i < 4; ++i) {
                const int c = c0 + ai * 16 + quad * 4 + i;
                const int m = m0 + bi * 16 + l16;
                const size_t idx = ((size_t)(b * CC + c)) * NT + m;
                outp[idx] = g * acc[i] + x[idx];
            }
        }
    }
}

extern "C" void kernel_launch(void* const* d_in, const int* in_sizes, int n_in,
                              void* d_out, int out_size, void* d_ws, size_t ws_size,
                              hipStream_t stream)
{
    const float* x     = (const float*)d_in[0];
    const float* valid = (const float*)d_in[1];
    const float* Wq    = (const float*)d_in[2];
    const float* bq    = (const float*)d_in[3];
    const float* Wk    = (const float*)d_in[4];
    const float* bk    = (const float*)d_in[5];
    const float* Wv    = (const float*)d_in[6];
    const float* bv    = (const float*)d_in[7];
    const float* gamma = (const float*)d_in[8];

    float* outp = (float*)d_out;
    float* sa   = outp + (size_t)BB * CC * NT;      // output chunk 1 [B][N][N] fp32

    u16* qh  = (u16*)d_ws;                          // [B][N][32]
    u16* ql  = qh  + (size_t)BB * NT * 32;
    u16* kh  = ql  + (size_t)BB * NT * 32;
    u16* kl  = kh  + (size_t)BB * NT * 32;
    u16* pvw = kl  + (size_t)BB * NT * 32;          // [B][C][N]
    u16* xth = pvw + (size_t)BB * CC * NT;          // [B][N][C]
    u16* xtl = xth + (size_t)BB * NT * CC;
    u16* wh  = xtl + (size_t)BB * NT * CC;          // [320][256]
    u16* wl  = wh  + (size_t)320 * 256;

    kwsplit<<<dim3(320), 256, 0, stream>>>(Wq, Wk, Wv, wh, wl);
    kcast<<<dim3(128, 8, BB), 256, 0, stream>>>(x, xth, xtl);
    kproj<<<dim3(128, 10, BB), 64, 0, stream>>>(wh, wl, xth, xtl, bq, bk, bv,
                                                qh, ql, kh, kl, pvw);
    kattn<<<dim3(64, BB), 256, 0, stream>>>(qh, ql, kh, kl, valid, sa);
    kout<<<dim3(128, BB), 512, 0, stream>>>(pvw, sa, x, gamma, outp);
}